// Round 3
// baseline (188.409 us; speedup 1.0000x reference)
//
#include <hip/hip_runtime.h>
#include <cstdint>
#include <cstddef>

// ---------------------------------------------------------------------------
// QLSTM on MI355X.
//
// Math: qlayer(ang)[w] = prod_{v in S_w} cos(ang_v), with S_w derived from the
// GF(2)-linear CNOT-ring permutation (DEPTH=2, 8 qubits, wire0=MSB).
// Verified three times (mask propagation of PERM^-1, Heisenberg conjugation of
// Z_w through the 16 CNOTs in reverse order, and a hand re-derivation):
//   S_0={0,1,3,5,7} S_1={0,2..7} S_2={1,3..7} S_3={0,2,4..7}
//   S_4={1,3,5,6,7} S_5={0,2,4,6,7} S_6={1,3,5,7} S_7={0,2,4,6}
// Packed little-endian byte-per-wire: 0x55AAD5EAF5FAFDAB.
// ---------------------------------------------------------------------------

constexpr int SEQ    = 128;
constexpr int NBATCH = 512;
constexpr int INDIM  = 64;
constexpr int FANIN  = 72;   // INPUT_DIM + HIDDEN_DIM
constexpr long OUT_HX = (long)SEQ * NBATCH * 8;        // outputs section size
constexpr long OUT_CX = OUT_HX + (long)NBATCH * 8;     // hx section follows

#define SWZ(v, imm) __int_as_float(__builtin_amdgcn_ds_swizzle(__float_as_int(v), (imm)))

// ---------------------------------------------------------------------------
// Kernel A: xp[t*512+b][gw] = sum_k x[t,b,k]*W_g[w,k] + b_g[w] + th_g[w]
// (k over the 64 input columns only; hidden columns handled in the scan).
// One thread per output element gw of one row; 8 rows per 256-thread block.
// ---------------------------------------------------------------------------
__global__ __launch_bounds__(256) void xproj_kernel(
    const float* __restrict__ x,
    const float* __restrict__ Wf, const float* __restrict__ bf, const float* __restrict__ thf,
    const float* __restrict__ Wi, const float* __restrict__ bi, const float* __restrict__ thi,
    const float* __restrict__ Wu, const float* __restrict__ bu, const float* __restrict__ thu,
    const float* __restrict__ Wo, const float* __restrict__ bo, const float* __restrict__ tho,
    float* __restrict__ xp)
{
    __shared__ float lx[8 * 64];
    const int tid = threadIdx.x;
    const long rowBase = (long)blockIdx.x * 8;

    // stage 8 rows of x (512 consecutive floats) — fully coalesced
    const float* xblk = x + rowBase * INDIM;
    lx[tid]       = xblk[tid];
    lx[tid + 256] = xblk[tid + 256];
    __syncthreads();

    const int r  = tid >> 5;        // local row 0..7
    const int gw = tid & 31;        // gate*8 + wire
    const int g  = gw >> 3;
    const int w  = gw & 7;

    const float* Wg = (g == 0) ? Wf : (g == 1) ? Wi : (g == 2) ? Wu : Wo;
    const float* bg = (g == 0) ? bf : (g == 1) ? bi : (g == 2) ? bu : bo;
    const float* tg = (g == 0) ? thf : (g == 1) ? thi : (g == 2) ? thu : tho;

    float acc = bg[w] + tg[w];
    const float4* Wrow = reinterpret_cast<const float4*>(Wg + w * FANIN); // 72*w*4B: 16B aligned
    const float4* xr   = reinterpret_cast<const float4*>(&lx[r * 64]);
#pragma unroll
    for (int k4 = 0; k4 < 16; ++k4) {
        const float4 wv = Wrow[k4];
        const float4 xv = xr[k4];     // same-address broadcast within 32-lane group
        acc = fmaf(xv.x, wv.x, acc);
        acc = fmaf(xv.y, wv.y, acc);
        acc = fmaf(xv.z, wv.z, acc);
        acc = fmaf(xv.w, wv.w, acc);
    }
    xp[(rowBase + r) * 32 + gw] = acc;   // coalesced: 256 consecutive floats/block
}

// ---------------------------------------------------------------------------
// Kernel B: the 128-step recurrence. 32 lanes per batch row (lane = g*8+w),
// 8 rows per 256-thread block, grid = 64 blocks. All cross-lane traffic via
// ds_swizzle BitMode (32-lane groups): src = ((lane & and) | or) ^ xor,
// imm = (xor<<10)|(or<<5)|and.
//   c-broadcast within gate group: and=0x18, or=j  -> (j<<5)|0x18
//   act gather (f/i/u/o of own wire): and=0x07, or=k*8 -> (k<<8)|0x07
//   hx broadcast from lanes 0..7:     and=0x00, or=j  -> (j<<5)
// xp is prefetched TWO steps ahead (L2-hit latency ~200cy ≈ one chain).
// FUSED=true fallback (ws too small): compute the x-projection inline from
// registers (64 W_x values per lane) — ~2x slower chain, no scratch needed.
// ---------------------------------------------------------------------------
template <bool FUSED>
__global__ __launch_bounds__(256) void qlstm_scan_kernel(
    const float* __restrict__ x,
    const float* __restrict__ xp,
    const float* __restrict__ Wf, const float* __restrict__ bf, const float* __restrict__ thf,
    const float* __restrict__ Wi, const float* __restrict__ bi, const float* __restrict__ thi,
    const float* __restrict__ Wu, const float* __restrict__ bu, const float* __restrict__ thu,
    const float* __restrict__ Wo, const float* __restrict__ bo, const float* __restrict__ tho,
    float* __restrict__ out)
{
    const int tid  = threadIdx.x;
    const int lane = tid & 31;
    const int row  = (blockIdx.x << 3) + (tid >> 5);   // batch index 0..511
    const int g    = lane >> 3;
    const int w    = lane & 7;

    const float* Wg = (g == 0) ? Wf : (g == 1) ? Wi : (g == 2) ? Wu : Wo;

    // hidden-state weights W_g[w][64..71]
    float wh0, wh1, wh2, wh3, wh4, wh5, wh6, wh7;
    {
        const float4* p = reinterpret_cast<const float4*>(Wg + w * FANIN + 64);
        const float4 a = p[0], b4 = p[1];
        wh0 = a.x; wh1 = a.y; wh2 = a.z; wh3 = a.w;
        wh4 = b4.x; wh5 = b4.y; wh6 = b4.z; wh7 = b4.w;
    }

    float bias = 0.f;
    float wx[64];
    if constexpr (FUSED) {
        const float* bg = (g == 0) ? bf : (g == 1) ? bi : (g == 2) ? bu : bo;
        const float* tg = (g == 0) ? thf : (g == 1) ? thi : (g == 2) ? thu : tho;
        bias = bg[w] + tg[w];
#pragma unroll
        for (int k4 = 0; k4 < 16; ++k4) {
            const float4 v = reinterpret_cast<const float4*>(Wg + w * FANIN)[k4];
            wx[4 * k4 + 0] = v.x; wx[4 * k4 + 1] = v.y;
            wx[4 * k4 + 2] = v.z; wx[4 * k4 + 3] = v.w;
        }
    }

    // per-wire Z-subset mask (see header comment)
    const unsigned mask = (unsigned)((0x55AAD5EAF5FAFDABull >> (w * 8)) & 0xFFull);

    float h0 = 0.f, h1 = 0.f, h2 = 0.f, h3 = 0.f, h4 = 0.f, h5 = 0.f, h6 = 0.f, h7 = 0.f;
    float cxl = 0.f;
    float nhx = 0.f;

    // two-deep rolling prefetch of the x-projection
    float xv0 = 0.f, xv1 = 0.f;
    if constexpr (!FUSED) {
        xv0 = xp[(long)row * 32 + lane];                       // t = 0
        xv1 = xp[((long)NBATCH + row) * 32 + lane];            // t = 1
    }

    for (int t = 0; t < SEQ; ++t) {
        float xv2 = 0.f;
        if constexpr (!FUSED) {
            if (t + 2 < SEQ) xv2 = xp[((long)(t + 2) * NBATCH + row) * 32 + lane];
        }

        float ang;
        if constexpr (FUSED) {
            const float4* xr4 = reinterpret_cast<const float4*>(x + ((long)t * NBATCH + row) * INDIM);
            float acc = bias;
#pragma unroll
            for (int k4 = 0; k4 < 16; ++k4) {
                const float4 v = xr4[k4];           // same-address broadcast per group
                acc = fmaf(v.x, wx[4 * k4 + 0], acc);
                acc = fmaf(v.y, wx[4 * k4 + 1], acc);
                acc = fmaf(v.z, wx[4 * k4 + 2], acc);
                acc = fmaf(v.w, wx[4 * k4 + 3], acc);
            }
            ang = acc;
        } else {
            ang = xv0;
        }

        // hidden dot: two chains for latency
        const float d0 = fmaf(h0, wh0, fmaf(h1, wh1, fmaf(h2, wh2, h3 * wh3)));
        const float d1 = fmaf(h4, wh4, fmaf(h5, wh5, fmaf(h6, wh6, h7 * wh7)));
        ang += d0 + d1;

        const float c = cosf(ang);

        // broadcast the 8 cosines of this lane's gate group
        const float cb0 = SWZ(c, 0x018);
        const float cb1 = SWZ(c, 0x038);
        const float cb2 = SWZ(c, 0x058);
        const float cb3 = SWZ(c, 0x078);
        const float cb4 = SWZ(c, 0x098);
        const float cb5 = SWZ(c, 0x0B8);
        const float cb6 = SWZ(c, 0x0D8);
        const float cb7 = SWZ(c, 0x0F8);

        // subset product via predicated selects + balanced tree
        const float p0 = (mask & 0x01u) ? cb0 : 1.0f;
        const float p1 = (mask & 0x02u) ? cb1 : 1.0f;
        const float p2 = (mask & 0x04u) ? cb2 : 1.0f;
        const float p3 = (mask & 0x08u) ? cb3 : 1.0f;
        const float p4 = (mask & 0x10u) ? cb4 : 1.0f;
        const float p5 = (mask & 0x20u) ? cb5 : 1.0f;
        const float p6 = (mask & 0x40u) ? cb6 : 1.0f;
        const float p7 = (mask & 0x80u) ? cb7 : 1.0f;
        const float z = ((p0 * p1) * (p2 * p3)) * ((p4 * p5) * (p6 * p7));

        // activation: sigmoid for f,i,o; tanh for u (= 2*sigmoid(2z)-1). z in [-1,1].
        const bool isU = (g == 2);
        const float zz = isU ? z + z : z;
        const float e  = expf(-zz);
        const float s  = 1.0f / (1.0f + e);
        const float act = isU ? fmaf(2.0f, s, -1.0f) : s;

        // gather this wire's four gate values (all lanes, keeps state replicated)
        const float fg = SWZ(act, 0x007);
        const float ig = SWZ(act, 0x107);
        const float ug = SWZ(act, 0x207);
        const float og = SWZ(act, 0x307);

        const float ncx = fmaf(fg, cxl, ig * ug);
        const float tc  = tanhf(ncx);
        nhx = og * tc;
        cxl = ncx;

        if (lane < 8) out[((long)t * NBATCH + row) * 8 + lane] = nhx;

        // broadcast new hidden state (lanes 0..7 hold wires 0..7)
        h0 = SWZ(nhx, 0x000);
        h1 = SWZ(nhx, 0x020);
        h2 = SWZ(nhx, 0x040);
        h3 = SWZ(nhx, 0x060);
        h4 = SWZ(nhx, 0x080);
        h5 = SWZ(nhx, 0x0A0);
        h6 = SWZ(nhx, 0x0C0);
        h7 = SWZ(nhx, 0x0E0);

        if constexpr (!FUSED) { xv0 = xv1; xv1 = xv2; }
    }

    if (lane < 8) {
        out[OUT_HX + (long)row * 8 + lane] = nhx;   // lane<8 => w==lane
        out[OUT_CX + (long)row * 8 + lane] = cxl;
    }
}

// ---------------------------------------------------------------------------
extern "C" void kernel_launch(void* const* d_in, const int* in_sizes, int n_in,
                              void* d_out, int out_size, void* d_ws, size_t ws_size,
                              hipStream_t stream)
{
    const float* x = (const float*)d_in[0];

    // Input ordering: setup_inputs() dict order is (W,b,th) per gate; the
    // reference signature order is all (W,b) then all th. Distinguish at
    // runtime: dict order has in_sizes[3]==8 (th_f), signature has 576 (W_i).
    const float *Wf, *bf, *thf, *Wi, *bi, *thi, *Wu, *bu, *thu, *Wo, *bo, *tho;
    if (in_sizes[3] == 8) {  // dict order: W_f,b_f,th_f, W_i,b_i,th_i, ...
        Wf = (const float*)d_in[1];  bf = (const float*)d_in[2];  thf = (const float*)d_in[3];
        Wi = (const float*)d_in[4];  bi = (const float*)d_in[5];  thi = (const float*)d_in[6];
        Wu = (const float*)d_in[7];  bu = (const float*)d_in[8];  thu = (const float*)d_in[9];
        Wo = (const float*)d_in[10]; bo = (const float*)d_in[11]; tho = (const float*)d_in[12];
    } else {                 // signature order: W_f,b_f, W_i,b_i, ..., th_f..th_o
        Wf = (const float*)d_in[1];  bf = (const float*)d_in[2];
        Wi = (const float*)d_in[3];  bi = (const float*)d_in[4];
        Wu = (const float*)d_in[5];  bu = (const float*)d_in[6];
        Wo = (const float*)d_in[7];  bo = (const float*)d_in[8];
        thf = (const float*)d_in[9]; thi = (const float*)d_in[10];
        thu = (const float*)d_in[11]; tho = (const float*)d_in[12];
    }

    float* out = (float*)d_out;
    float* xp  = (float*)d_ws;
    const size_t need = (size_t)SEQ * NBATCH * 32 * sizeof(float);  // 8.4 MB

    if (ws_size >= need) {
        xproj_kernel<<<(SEQ * NBATCH) / 8, 256, 0, stream>>>(
            x, Wf, bf, thf, Wi, bi, thi, Wu, bu, thu, Wo, bo, tho, xp);
        qlstm_scan_kernel<false><<<NBATCH / 8, 256, 0, stream>>>(
            x, xp, Wf, bf, thf, Wi, bi, thi, Wu, bu, thu, Wo, bo, tho, out);
    } else {
        qlstm_scan_kernel<true><<<NBATCH / 8, 256, 0, stream>>>(
            x, nullptr, Wf, bf, thf, Wi, bi, thi, Wu, bu, thu, Wo, bo, tho, out);
    }
}

// Round 5
// 159.668 us; speedup vs baseline: 1.1800x; 1.1800x over previous
//
#include <hip/hip_runtime.h>
#include <cstdint>
#include <cstddef>

// ---------------------------------------------------------------------------
// QLSTM on MI355X.
//
// Math: qlayer(ang)[w] = prod_{v in S_w} cos(ang_v), with S_w derived from the
// GF(2)-linear CNOT-ring permutation (DEPTH=2, 8 qubits, wire0=MSB).
// Verified three times (mask propagation of PERM^-1, Heisenberg conjugation of
// Z_w through the 16 CNOTs in reverse order, and a hand re-derivation):
//   S_0={0,1,3,5,7} S_1={0,2..7} S_2={1,3..7} S_3={0,2,4..7}
//   S_4={1,3,5,6,7} S_5={0,2,4,6,7} S_6={1,3,5,7} S_7={0,2,4,6}
// Packed little-endian byte-per-wire: 0x55AAD5EAF5FAFDAB.
//
// R3 measurements: scan 72us (chain ~1350cy/step, libm transcendentals),
// xproj inferred ~50-70us (L1 W-gather bound). R4: native v_cos/v_exp/v_rcp
// on the scan chain; register-tiled xproj (2 rows x 8 outs per thread).
// ---------------------------------------------------------------------------

constexpr int SEQ    = 128;
constexpr int NBATCH = 512;
constexpr int INDIM  = 64;
constexpr int FANIN  = 72;   // INPUT_DIM + HIDDEN_DIM
constexpr long OUT_HX = (long)SEQ * NBATCH * 8;        // outputs section size
constexpr long OUT_CX = OUT_HX + (long)NBATCH * 8;     // hx section follows

#define SWZ(v, imm) __int_as_float(__builtin_amdgcn_ds_swizzle(__float_as_int(v), (imm)))

__device__ __forceinline__ float fast_cos(float ang) {
    // cos(ang) = v_cos(fract(ang / 2pi)); v_cos takes revolutions in [0,1).
    const float rev = ang * 0.15915494309189535f;
    return __builtin_amdgcn_cosf(__builtin_amdgcn_fractf(rev));
}

// ---------------------------------------------------------------------------
// Kernel A (v2): xp[t*512+b][gw] = sum_k x[t,b,k]*W_g[w,k] + b_g[w] + th_g[w]
// (k over the 64 input columns only; hidden columns handled in the scan).
// 512 blocks x 256 threads; block stages 128 rows of x in LDS (pad 68 ->
// b128 reads are 2-way-conflict = free). Thread (og = tid&3, q = tid>>2)
// computes rows {q, q+64} x outputs {og*8 .. og*8+7}: 64 FMA per 10 loads.
// W rows (72 floats = 288B, 16B-aligned) read as wave-uniform float4 from L1.
// ---------------------------------------------------------------------------
__global__ __launch_bounds__(256) void xproj_kernel(
    const float* __restrict__ x,
    const float* __restrict__ Wf, const float* __restrict__ bf, const float* __restrict__ thf,
    const float* __restrict__ Wi, const float* __restrict__ bi, const float* __restrict__ thi,
    const float* __restrict__ Wu, const float* __restrict__ bu, const float* __restrict__ thu,
    const float* __restrict__ Wo, const float* __restrict__ bo, const float* __restrict__ tho,
    float* __restrict__ xp)
{
    __shared__ float lx[128 * 68];      // 34816 B
    __shared__ float lbias[32];
    const int tid = threadIdx.x;
    const long rowBase = (long)blockIdx.x * 128;

    if (tid < 32) {
        const int g = tid >> 3, w = tid & 7;
        const float* bg = (g == 0) ? bf : (g == 1) ? bi : (g == 2) ? bu : bo;
        const float* tg = (g == 0) ? thf : (g == 1) ? thi : (g == 2) ? thu : tho;
        lbias[tid] = bg[w] + tg[w];
    }

    // stage 128 rows (32 KB contiguous) via coalesced float4
    const float4* xin = reinterpret_cast<const float4*>(x + rowBase * INDIM);
#pragma unroll
    for (int i = 0; i < 8; ++i) {
        const int f   = i * 256 + tid;       // float4 index 0..2047
        const int row = f >> 4;
        const int kq  = f & 15;
        *reinterpret_cast<float4*>(&lx[row * 68 + kq * 4]) = xin[f];
    }
    __syncthreads();

    const int og = tid & 3;              // gate (octet of outputs)
    const int q  = tid >> 2;             // 0..63 (row within half-tile)
    const float* Wg = (og == 0) ? Wf : (og == 1) ? Wi : (og == 2) ? Wu : Wo;

    float acc[2][8];
#pragma unroll
    for (int r = 0; r < 2; ++r)
#pragma unroll
        for (int j = 0; j < 8; ++j) acc[r][j] = 0.f;

#pragma unroll
    for (int k4 = 0; k4 < 16; ++k4) {
        const float4 x0 = *reinterpret_cast<const float4*>(&lx[q * 68 + k4 * 4]);
        const float4 x1 = *reinterpret_cast<const float4*>(&lx[(q + 64) * 68 + k4 * 4]);
#pragma unroll
        for (int j = 0; j < 8; ++j) {
            const float4 wv = *reinterpret_cast<const float4*>(Wg + j * FANIN + k4 * 4);
            acc[0][j] = fmaf(x0.x, wv.x, acc[0][j]);
            acc[0][j] = fmaf(x0.y, wv.y, acc[0][j]);
            acc[0][j] = fmaf(x0.z, wv.z, acc[0][j]);
            acc[0][j] = fmaf(x0.w, wv.w, acc[0][j]);
            acc[1][j] = fmaf(x1.x, wv.x, acc[1][j]);
            acc[1][j] = fmaf(x1.y, wv.y, acc[1][j]);
            acc[1][j] = fmaf(x1.z, wv.z, acc[1][j]);
            acc[1][j] = fmaf(x1.w, wv.w, acc[1][j]);
        }
    }

#pragma unroll
    for (int r = 0; r < 2; ++r) {
        float4 o0, o1;
        o0.x = acc[r][0] + lbias[og * 8 + 0];
        o0.y = acc[r][1] + lbias[og * 8 + 1];
        o0.z = acc[r][2] + lbias[og * 8 + 2];
        o0.w = acc[r][3] + lbias[og * 8 + 3];
        o1.x = acc[r][4] + lbias[og * 8 + 4];
        o1.y = acc[r][5] + lbias[og * 8 + 5];
        o1.z = acc[r][6] + lbias[og * 8 + 6];
        o1.w = acc[r][7] + lbias[og * 8 + 7];
        float* dst = xp + (rowBase + q + 64 * r) * 32 + og * 8;
        reinterpret_cast<float4*>(dst)[0] = o0;
        reinterpret_cast<float4*>(dst)[1] = o1;
    }
}

// ---------------------------------------------------------------------------
// Kernel B: the 128-step recurrence. 32 lanes per batch row (lane = g*8+w),
// 8 rows per 256-thread block, grid = 64 blocks. All cross-lane traffic via
// ds_swizzle BitMode (32-lane groups): src = ((lane & and) | or) ^ xor,
// imm = (xor<<10)|(or<<5)|and.
//   c-broadcast within gate group: and=0x18, or=j  -> (j<<5)|0x18
//   act gather (f/i/u/o of own wire): and=0x07, or=k*8 -> (k<<8)|0x07
//   hx broadcast from lanes 0..7:     and=0x00, or=j  -> (j<<5)
// xp is prefetched TWO steps ahead. All transcendentals are native HW ops
// (v_cos/v_exp/v_rcp) -- R3 showed libm calls dominated the serial chain.
// FUSED=true fallback (ws too small): x-projection inline from registers.
// ---------------------------------------------------------------------------
template <bool FUSED>
__global__ __launch_bounds__(256) void qlstm_scan_kernel(
    const float* __restrict__ x,
    const float* __restrict__ xp,
    const float* __restrict__ Wf, const float* __restrict__ bf, const float* __restrict__ thf,
    const float* __restrict__ Wi, const float* __restrict__ bi, const float* __restrict__ thi,
    const float* __restrict__ Wu, const float* __restrict__ bu, const float* __restrict__ thu,
    const float* __restrict__ Wo, const float* __restrict__ bo, const float* __restrict__ tho,
    float* __restrict__ out)
{
    const int tid  = threadIdx.x;
    const int lane = tid & 31;
    const int row  = (blockIdx.x << 3) + (tid >> 5);   // batch index 0..511
    const int g    = lane >> 3;
    const int w    = lane & 7;

    const float* Wg = (g == 0) ? Wf : (g == 1) ? Wi : (g == 2) ? Wu : Wo;

    // hidden-state weights W_g[w][64..71]
    float wh0, wh1, wh2, wh3, wh4, wh5, wh6, wh7;
    {
        const float4* p = reinterpret_cast<const float4*>(Wg + w * FANIN + 64);
        const float4 a = p[0], b4 = p[1];
        wh0 = a.x; wh1 = a.y; wh2 = a.z; wh3 = a.w;
        wh4 = b4.x; wh5 = b4.y; wh6 = b4.z; wh7 = b4.w;
    }

    float bias = 0.f;
    float wx[64];
    if constexpr (FUSED) {
        const float* bg = (g == 0) ? bf : (g == 1) ? bi : (g == 2) ? bu : bo;
        const float* tg = (g == 0) ? thf : (g == 1) ? thi : (g == 2) ? thu : tho;
        bias = bg[w] + tg[w];
#pragma unroll
        for (int k4 = 0; k4 < 16; ++k4) {
            const float4 v = reinterpret_cast<const float4*>(Wg + w * FANIN)[k4];
            wx[4 * k4 + 0] = v.x; wx[4 * k4 + 1] = v.y;
            wx[4 * k4 + 2] = v.z; wx[4 * k4 + 3] = v.w;
        }
    }

    // per-wire Z-subset mask (see header comment)
    const unsigned mask = (unsigned)((0x55AAD5EAF5FAFDABull >> (w * 8)) & 0xFFull);

    // activation constants, hoisted so no select sits on the serial chain:
    // f,i,o: sigmoid(z) = rcp(1+exp(-z));  u: tanh(z) = 2*rcp(1+exp(-2z))-1
    const bool  isU = (g == 2);
    const float ZL  = isU ? -2.0f : -1.0f;   // exp multiplier
    const float A   = isU ?  2.0f :  1.0f;
    const float B   = isU ? -1.0f :  0.0f;

    float h0 = 0.f, h1 = 0.f, h2 = 0.f, h3 = 0.f, h4 = 0.f, h5 = 0.f, h6 = 0.f, h7 = 0.f;
    float cxl = 0.f;
    float nhx = 0.f;

    // two-deep rolling prefetch of the x-projection
    float xv0 = 0.f, xv1 = 0.f;
    if constexpr (!FUSED) {
        xv0 = xp[(long)row * 32 + lane];                       // t = 0
        xv1 = xp[((long)NBATCH + row) * 32 + lane];            // t = 1
    }

    for (int t = 0; t < SEQ; ++t) {
        float xv2 = 0.f;
        if constexpr (!FUSED) {
            if (t + 2 < SEQ) xv2 = xp[((long)(t + 2) * NBATCH + row) * 32 + lane];
        }

        float ang;
        if constexpr (FUSED) {
            const float4* xr4 = reinterpret_cast<const float4*>(x + ((long)t * NBATCH + row) * INDIM);
            float acc = bias;
#pragma unroll
            for (int k4 = 0; k4 < 16; ++k4) {
                const float4 v = xr4[k4];           // same-address broadcast per group
                acc = fmaf(v.x, wx[4 * k4 + 0], acc);
                acc = fmaf(v.y, wx[4 * k4 + 1], acc);
                acc = fmaf(v.z, wx[4 * k4 + 2], acc);
                acc = fmaf(v.w, wx[4 * k4 + 3], acc);
            }
            ang = acc;
        } else {
            ang = xv0;
        }

        // hidden dot: two chains for latency
        const float d0 = fmaf(h0, wh0, fmaf(h1, wh1, fmaf(h2, wh2, h3 * wh3)));
        const float d1 = fmaf(h4, wh4, fmaf(h5, wh5, fmaf(h6, wh6, h7 * wh7)));
        ang += d0 + d1;

        const float c = fast_cos(ang);

        // broadcast the 8 cosines of this lane's gate group
        const float cb0 = SWZ(c, 0x018);
        const float cb1 = SWZ(c, 0x038);
        const float cb2 = SWZ(c, 0x058);
        const float cb3 = SWZ(c, 0x078);
        const float cb4 = SWZ(c, 0x098);
        const float cb5 = SWZ(c, 0x0B8);
        const float cb6 = SWZ(c, 0x0D8);
        const float cb7 = SWZ(c, 0x0F8);

        // subset product via predicated selects + balanced tree
        const float p0 = (mask & 0x01u) ? cb0 : 1.0f;
        const float p1 = (mask & 0x02u) ? cb1 : 1.0f;
        const float p2 = (mask & 0x04u) ? cb2 : 1.0f;
        const float p3 = (mask & 0x08u) ? cb3 : 1.0f;
        const float p4 = (mask & 0x10u) ? cb4 : 1.0f;
        const float p5 = (mask & 0x20u) ? cb5 : 1.0f;
        const float p6 = (mask & 0x40u) ? cb6 : 1.0f;
        const float p7 = (mask & 0x80u) ? cb7 : 1.0f;
        const float z = ((p0 * p1) * (p2 * p3)) * ((p4 * p5) * (p6 * p7));

        // activation via native exp/rcp (constants hoisted above)
        const float e   = __expf(z * ZL);
        const float s   = __builtin_amdgcn_rcpf(1.0f + e);
        const float act = fmaf(A, s, B);

        // gather this wire's four gate values (all lanes, keeps state replicated)
        const float fg = SWZ(act, 0x007);
        const float ig = SWZ(act, 0x107);
        const float ug = SWZ(act, 0x207);
        const float og = SWZ(act, 0x307);

        const float ncx = fmaf(fg, cxl, ig * ug);
        // tanh(ncx) = 2*rcp(1+exp(-2*ncx)) - 1
        const float et  = __expf(-2.0f * ncx);
        const float tc  = fmaf(2.0f, __builtin_amdgcn_rcpf(1.0f + et), -1.0f);
        nhx = og * tc;
        cxl = ncx;

        if (lane < 8) out[((long)t * NBATCH + row) * 8 + lane] = nhx;

        // broadcast new hidden state (lanes 0..7 hold wires 0..7)
        h0 = SWZ(nhx, 0x000);
        h1 = SWZ(nhx, 0x020);
        h2 = SWZ(nhx, 0x040);
        h3 = SWZ(nhx, 0x060);
        h4 = SWZ(nhx, 0x080);
        h5 = SWZ(nhx, 0x0A0);
        h6 = SWZ(nhx, 0x0C0);
        h7 = SWZ(nhx, 0x0E0);

        if constexpr (!FUSED) { xv0 = xv1; xv1 = xv2; }
    }

    if (lane < 8) {
        out[OUT_HX + (long)row * 8 + lane] = nhx;   // lane<8 => w==lane
        out[OUT_CX + (long)row * 8 + lane] = cxl;
    }
}

// ---------------------------------------------------------------------------
extern "C" void kernel_launch(void* const* d_in, const int* in_sizes, int n_in,
                              void* d_out, int out_size, void* d_ws, size_t ws_size,
                              hipStream_t stream)
{
    const float* x = (const float*)d_in[0];

    // Input ordering: setup_inputs() dict order is (W,b,th) per gate; the
    // reference signature order is all (W,b) then all th. Distinguish at
    // runtime: dict order has in_sizes[3]==8 (th_f), signature has 576 (W_i).
    const float *Wf, *bf, *thf, *Wi, *bi, *thi, *Wu, *bu, *thu, *Wo, *bo, *tho;
    if (in_sizes[3] == 8) {  // dict order: W_f,b_f,th_f, W_i,b_i,th_i, ...
        Wf = (const float*)d_in[1];  bf = (const float*)d_in[2];  thf = (const float*)d_in[3];
        Wi = (const float*)d_in[4];  bi = (const float*)d_in[5];  thi = (const float*)d_in[6];
        Wu = (const float*)d_in[7];  bu = (const float*)d_in[8];  thu = (const float*)d_in[9];
        Wo = (const float*)d_in[10]; bo = (const float*)d_in[11]; tho = (const float*)d_in[12];
    } else {                 // signature order: W_f,b_f, W_i,b_i, ..., th_f..th_o
        Wf = (const float*)d_in[1];  bf = (const float*)d_in[2];
        Wi = (const float*)d_in[3];  bi = (const float*)d_in[4];
        Wu = (const float*)d_in[5];  bu = (const float*)d_in[6];
        Wo = (const float*)d_in[7];  bo = (const float*)d_in[8];
        thf = (const float*)d_in[9]; thi = (const float*)d_in[10];
        thu = (const float*)d_in[11]; tho = (const float*)d_in[12];
    }

    float* out = (float*)d_out;
    float* xp  = (float*)d_ws;
    const size_t need = (size_t)SEQ * NBATCH * 32 * sizeof(float);  // 8.4 MB

    if (ws_size >= need) {
        xproj_kernel<<<(SEQ * NBATCH) / 128, 256, 0, stream>>>(
            x, Wf, bf, thf, Wi, bi, thi, Wu, bu, thu, Wo, bo, tho, xp);
        qlstm_scan_kernel<false><<<NBATCH / 8, 256, 0, stream>>>(
            x, xp, Wf, bf, thf, Wi, bi, thi, Wu, bu, thu, Wo, bo, tho, out);
    } else {
        qlstm_scan_kernel<true><<<NBATCH / 8, 256, 0, stream>>>(
            x, nullptr, Wf, bf, thf, Wi, bi, thi, Wu, bu, thu, Wo, bo, tho, out);
    }
}